// Round 9
// baseline (569.971 us; speedup 1.0000x reference)
//
#include <hip/hip_runtime.h>
#include <hip/hip_fp16.h>
#include <math.h>

// Problem constants: tenIn [8,64,288,512] fp32, flow [8,2,H,W], metric [8,1,H,W].
constexpr int N  = 8;
constexpr int C  = 64;
constexpr int H  = 288;
constexpr int W  = 512;               // power of 2
constexpr int HW = H * W;             // 147456
constexpr int NPIX = N * HW;          // 1,179,648

// Output tiling. R covers max corner displacement for this data; escape path
// handles anything larger exactly, so R is perf-only.
constexpr int TW = 64, TH = 32, R = 8;
constexpr int PW = TW + 2 * R;        // 80
constexpr int PH = TH + 2 * R;        // 48
constexpr int PS = PW * PH;           // 3840 (fits u16)
constexpr int TGX = W / TW;           // 8
constexpr int TGY = H / TH;           // 9
constexpr int TILES = N * TGX * TGY;  // 576
constexpr int NOUT = TH * TW;         // 2048 outputs per tile
constexpr int K = 12;                 // reg-resident slots per output
constexpr int CCHB = 8;               // channels per gather chunk (8 x f16 = 16B)
constexpr int NCHUNK = C / CCHB;      // 8
constexpr int NSPLIT = 2;             // channel-halves across blocks
constexpr int CPB = NCHUNK / NSPLIT;  // 4 chunks per gather block
constexpr int OVFCAP = 256;           // per-tile overflow entries (slot > K)
constexpr int ESCCAP = 512;           // per-tile escape entries (|disp| > R)
constexpr int NTC = 512;              // claim threads
constexpr int NTG = 1024;             // gather threads (16 waves/block)
constexpr int GGRID = TILES * NSPLIT; // 1152 = 8 XCDs * 144

// Workspace layout (4-byte words). Total ~70.8 MB.
constexpr size_t WS_DEN  = 0;                                  // N*HW f32
constexpr size_t WS_META = WS_DEN  + (size_t)N * HW;           // TILES*K*NOUT u32 (slot-major)
constexpr size_t WS_CNT  = WS_META + (size_t)TILES * NOUT * K; // TILES*NOUT u32
constexpr size_t WS_OVFC = WS_CNT  + (size_t)TILES * NOUT;     // TILES u32
constexpr size_t WS_OVFE = WS_OVFC + TILES;                    // TILES*OVFCAP*2
constexpr size_t WS_ESCC = WS_OVFE + (size_t)TILES * OVFCAP * 2; // TILES u32
constexpr size_t WS_ESCE = WS_ESCC + TILES;                    // TILES*ESCCAP*3

__device__ __forceinline__ int swz(int si) { return si ^ ((si >> 3) & 7); }

__device__ __forceinline__ unsigned packh2(float a, float b) {
    __half2 h = __floats2half2_rn(a, b);
    return *reinterpret_cast<unsigned*>(&h);
}
__device__ __forceinline__ float2 unpackh2(unsigned u) {
    __half2 h = *reinterpret_cast<__half2*>(&u);
    return __half22float2(h);
}

// ---------------------------------------------------------------------------
// Kernel 1: per-tile claim. Each (src,corner) landing in-tile claims a slot
// via LDS atomic; meta is slot-major [t][s][o] (coalesced gather reads).
// Also computes den per output (slot + overflow weight sum), plain store.
// ---------------------------------------------------------------------------
__global__ __launch_bounds__(NTC) void claim_kernel(
    const float* __restrict__ flow, const float* __restrict__ metric,
    unsigned* __restrict__ meta, unsigned* __restrict__ cntg,
    unsigned* __restrict__ ovfc, unsigned* __restrict__ ovfe,
    float* __restrict__ den)
{
    __shared__ unsigned cnt[NOUT];     // 8 KB
    for (int i = threadIdx.x; i < NOUT; i += NTC) cnt[i] = 0;
    __syncthreads();

    const int t  = blockIdx.x;
    const int n  = t / (TGX * TGY);
    const int r  = t % (TGX * TGY);
    const int Y0 = (r / TGX) * TH;
    const int X0 = (r % TGX) * TW;

    const float* fxp = flow + ((size_t)n * 2) * HW;
    const float* fyp = fxp + HW;
    const float* mp  = metric + (size_t)n * HW;
    unsigned* mt = meta + (size_t)t * K * NOUT;

    for (int si = threadIdx.x; si < PS; si += NTC) {
        int ys = Y0 - R + si / PW;
        int xs = X0 - R + si % PW;
        if ((unsigned)ys >= (unsigned)H || (unsigned)xs >= (unsigned)W) continue;
        int p = ys * W + xs;
        float fx = fxp[p] + (float)xs;
        float fy = fyp[p] + (float)ys;
        if (!(isfinite(fx) && isfinite(fy))) continue;
        float x0f = floorf(fx), y0f = floorf(fy);
        int tx = (int)x0f - X0;
        int ty = (int)y0f - Y0;
        float wx1 = fx - x0f, wx0 = x0f + 1.0f - fx;
        float wy1 = fy - y0f, wy0 = y0f + 1.0f - fy;
        float wm  = __expf(mp[p]);

        #define CLAIM(TYv, TXv, Wv)                                           \
            if ((unsigned)(TYv) < (unsigned)TH &&                             \
                (unsigned)(TXv) < (unsigned)TW) {                             \
                float w_ = (Wv) * wm;                                         \
                int   o_ = (TYv) * TW + (TXv);                                \
                unsigned slot = atomicAdd(&cnt[o_], 1u);                      \
                if (slot < (unsigned)K) {                                     \
                    mt[(size_t)slot * NOUT + o_] =                            \
                        ((unsigned)__half_as_ushort(__float2half(w_)) << 16)  \
                        | (unsigned)si;                                       \
                } else {                                                      \
                    unsigned p2 = atomicAdd(&ovfc[t], 1u);                    \
                    if (p2 < (unsigned)OVFCAP) {                              \
                        unsigned* e = ovfe + ((size_t)t * OVFCAP + p2) * 2;   \
                        e[0] = ((unsigned)o_ << 16) | (unsigned)si;           \
                        e[1] = __float_as_uint(w_);                           \
                    }                                                         \
                }                                                             \
            }
        CLAIM(ty,     tx,     wx0 * wy0)
        CLAIM(ty,     tx + 1, wx1 * wy0)
        CLAIM(ty + 1, tx,     wx0 * wy1)
        CLAIM(ty + 1, tx + 1, wx1 * wy1)
        #undef CLAIM
    }
    __syncthreads();

    const unsigned on = min(ovfc[t], (unsigned)OVFCAP);
    const unsigned* oe = ovfe + (size_t)t * OVFCAP * 2;
    for (int o = threadIdx.x; o < NOUT; o += NTC) {
        unsigned craw = cnt[o];
        cntg[(size_t)t * NOUT + o] = craw;
        unsigned cn = min(craw, (unsigned)K);
        float d = 0.0f;
        for (unsigned s = 0; s < cn; ++s)
            d += __half2float(__ushort_as_half(
                     (unsigned short)(mt[(size_t)s * NOUT + o] >> 16)));
        for (unsigned i = 0; i < on; ++i)
            if ((oe[2 * i] >> 16) == (unsigned)o)
                d += __uint_as_float(oe[2 * i + 1]);
        den[(size_t)n * HW + (Y0 + o / TW) * W + X0 + o % TW] = d;
    }
}

// ---------------------------------------------------------------------------
// Kernel 2: escape (exact complement). Empty for this data.
// ---------------------------------------------------------------------------
__global__ __launch_bounds__(256) void escape_kernel(
    const float* __restrict__ flow, const float* __restrict__ metric,
    float* __restrict__ den, unsigned* __restrict__ escc,
    unsigned* __restrict__ esce)
{
    int pix = blockIdx.x * 256 + threadIdx.x;
    if (pix >= NPIX) return;
    int n  = pix / HW;
    int p  = pix - n * HW;
    int xs = p & (W - 1);
    int ys = p >> 9;

    float fx = flow[((size_t)n * 2    ) * HW + p] + (float)xs;
    float fy = flow[((size_t)n * 2 + 1) * HW + p] + (float)ys;
    if (!(isfinite(fx) && isfinite(fy))) return;
    float x0f = floorf(fx), y0f = floorf(fy);
    int ix0 = (int)x0f, iy0 = (int)y0f;
    float wx1 = fx - x0f, wx0 = x0f + 1.0f - fx;
    float wy1 = fy - y0f, wy0 = y0f + 1.0f - fy;

    int   cx[4] = { ix0, ix0 + 1, ix0,     ix0 + 1 };
    int   cy[4] = { iy0, iy0,     iy0 + 1, iy0 + 1 };
    float cw[4] = { wx0 * wy0, wx1 * wy0, wx0 * wy1, wx1 * wy1 };

    bool esc[4]; bool any = false;
    #pragma unroll
    for (int k = 0; k < 4; ++k) {
        esc[k] = false;
        if ((unsigned)cx[k] < (unsigned)W && (unsigned)cy[k] < (unsigned)H) {
            int tX0 = cx[k] & ~(TW - 1);
            int tY0 = cy[k] & ~(TH - 1);
            bool inpad = (xs >= tX0 - R) && (xs < tX0 + TW + R) &&
                         (ys >= tY0 - R) && (ys < tY0 + TH + R);
            if (!inpad) { esc[k] = true; any = true; }
        }
    }
    if (!any) return;

    float wm = __expf(metric[(size_t)n * HW + p]);
    #pragma unroll
    for (int k = 0; k < 4; ++k) {
        if (!esc[k]) continue;
        int tX0 = cx[k] & ~(TW - 1);
        int tY0 = cy[k] & ~(TH - 1);
        int tt  = n * (TGX * TGY) + (tY0 >> 5) * TGX + (tX0 >> 6);
        float w_ = cw[k] * wm;
        atomicAdd(den + (size_t)n * HW + cy[k] * W + cx[k], w_);
        unsigned pos = atomicAdd(&escc[tt], 1u);
        if (pos < (unsigned)ESCCAP) {
            unsigned* e = esce + ((size_t)tt * ESCCAP + pos) * 3;
            e[0] = (unsigned)((cy[k] - tY0) * TW + (cx[k] - tX0));
            e[1] = (unsigned)p;
            e[2] = __float_as_uint(w_);
        }
    }
}

// ---------------------------------------------------------------------------
// Kernel 3: gather + fused normalize. Block (tile t, channel-half split),
// XCD-swizzled (each XCD owns one image). LDS entry val[si] = 16B of EIGHT
// f16 channel values (was 4 x f32): one random ds_read_b128 per slot now
// serves 8 channels -> half the random-gather instructions, which R8's cycle
// model showed are the kernel's critical path. Staging: two 4-plane register
// phases, converting to packed half2 (VGPR-safe, no spills at <=128 cap).
// Fused 1/den; out written exactly once, coalesced.
// ---------------------------------------------------------------------------
__global__ __launch_bounds__(NTG, 4) void gather_kernel(
    const float* __restrict__ in, const unsigned* __restrict__ meta,
    const unsigned* __restrict__ cntg, const unsigned* __restrict__ ovfc,
    const unsigned* __restrict__ ovfe, const unsigned* __restrict__ escc,
    const unsigned* __restrict__ esce, const float* __restrict__ den,
    float* __restrict__ out)
{
    __shared__ uint4 val[PS];   // 61440 B: 8 x f16 channels per entry

    const int b0 = blockIdx.x;
    const int b  = (b0 & 7) * (GGRID / 8) + (b0 >> 3);
    const int t     = b >> 1;
    const int split = b & 1;
    const int n  = t / (TGX * TGY);
    const int r  = t % (TGX * TGY);
    const int Y0 = (r / TGX) * TH;
    const int X0 = (r % TGX) * TW;

    const unsigned on = min(ovfc[t], (unsigned)OVFCAP);
    const unsigned en = min(escc[t], (unsigned)ESCCAP);
    const unsigned* oe = ovfe + (size_t)t * OVFCAP * 2;
    const unsigned* ee = esce + (size_t)t * ESCCAP * 3;
    const unsigned* mt = meta + (size_t)t * K * NOUT;

    unsigned mm[2][K];
    float    inv[2];
    int      opix[2];
    #pragma unroll
    for (int k = 0; k < 2; ++k) {
        int o = threadIdx.x + k * NTG;
        unsigned cn = min(cntg[(size_t)t * NOUT + o], (unsigned)K);
        #pragma unroll
        for (int s = 0; s < K; ++s)
            mm[k][s] = (s < (int)cn) ? mt[(size_t)s * NOUT + o] : 0u;
        opix[k] = (Y0 + o / TW) * W + X0 + o % TW;
        float d = den[(size_t)n * HW + opix[k]];
        inv[k] = (d == 0.0f) ? 1.0f : 1.0f / d;
    }

    for (int cc = 0; cc < CPB; ++cc) {
        const int cb = split * CPB + cc;             // 8-channel group index
        const float* inb = in + ((size_t)n * C + cb * CCHB) * HW;
        __syncthreads();   // protect val from previous chunk's readers
        if (threadIdx.x < PS / 4) {        // 960 staging threads
            int si0 = threadIdx.x * 4;
            int row = si0 / PW;            // quads never straddle rows (80%4==0)
            int ys  = Y0 - R + row;
            int xs0 = X0 - R + (si0 - row * PW);
            bool ok = (unsigned)ys < (unsigned)H && (unsigned)xs0 < (unsigned)W;
            const float* pp = inb + ys * W + xs0;
            uint2* v2 = reinterpret_cast<uint2*>(val);
            int sw = (si0 >> 3) & 7;       // si0..si0+3 share swizzle bits
            {   // planes 0..3 -> low 8 bytes (channels c0..c3 as f16)
                float4 g0 = {0,0,0,0}, g1 = g0, g2 = g0, g3 = g0;
                if (ok) {
                    g0 = *reinterpret_cast<const float4*>(pp);
                    g1 = *reinterpret_cast<const float4*>(pp + HW);
                    g2 = *reinterpret_cast<const float4*>(pp + 2 * HW);
                    g3 = *reinterpret_cast<const float4*>(pp + 3 * HW);
                }
                v2[(((si0    ) ^ sw) << 1)] = make_uint2(packh2(g0.x, g1.x), packh2(g2.x, g3.x));
                v2[(((si0 + 1) ^ sw) << 1)] = make_uint2(packh2(g0.y, g1.y), packh2(g2.y, g3.y));
                v2[(((si0 + 2) ^ sw) << 1)] = make_uint2(packh2(g0.z, g1.z), packh2(g2.z, g3.z));
                v2[(((si0 + 3) ^ sw) << 1)] = make_uint2(packh2(g0.w, g1.w), packh2(g2.w, g3.w));
            }
            {   // planes 4..7 -> high 8 bytes (channels c4..c7 as f16)
                float4 g4 = {0,0,0,0}, g5 = g4, g6 = g4, g7 = g4;
                if (ok) {
                    g4 = *reinterpret_cast<const float4*>(pp + 4 * HW);
                    g5 = *reinterpret_cast<const float4*>(pp + 5 * HW);
                    g6 = *reinterpret_cast<const float4*>(pp + 6 * HW);
                    g7 = *reinterpret_cast<const float4*>(pp + 7 * HW);
                }
                v2[(((si0    ) ^ sw) << 1) | 1] = make_uint2(packh2(g4.x, g5.x), packh2(g6.x, g7.x));
                v2[(((si0 + 1) ^ sw) << 1) | 1] = make_uint2(packh2(g4.y, g5.y), packh2(g6.y, g7.y));
                v2[(((si0 + 2) ^ sw) << 1) | 1] = make_uint2(packh2(g4.z, g5.z), packh2(g6.z, g7.z));
                v2[(((si0 + 3) ^ sw) << 1) | 1] = make_uint2(packh2(g4.w, g5.w), packh2(g6.w, g7.w));
            }
        }
        __syncthreads();

        #pragma unroll
        for (int k = 0; k < 2; ++k) {
            float acc[CCHB];
            #pragma unroll
            for (int c = 0; c < CCHB; ++c) acc[c] = 0.0f;
            #pragma unroll
            for (int s = 0; s < K; ++s) {
                unsigned m_ = mm[k][s];
                float w  = __half2float(__ushort_as_half((unsigned short)(m_ >> 16)));
                int   si = (int)(m_ & 0xffffu);
                uint4 v = val[swz(si)];
                float2 f0 = unpackh2(v.x), f1 = unpackh2(v.y);
                float2 f2 = unpackh2(v.z), f3 = unpackh2(v.w);
                acc[0] += w * f0.x;  acc[1] += w * f0.y;
                acc[2] += w * f1.x;  acc[3] += w * f1.y;
                acc[4] += w * f2.x;  acc[5] += w * f2.y;
                acc[6] += w * f3.x;  acc[7] += w * f3.y;
            }
            int o = threadIdx.x + k * NTG;
            for (unsigned i = 0; i < on; ++i) {          // usually 0-3 entries
                unsigned e0 = oe[2 * i];
                if ((e0 >> 16) == (unsigned)o) {
                    float w  = __uint_as_float(oe[2 * i + 1]);
                    uint4 v = val[swz((int)(e0 & 0xffffu))];
                    float2 f0 = unpackh2(v.x), f1 = unpackh2(v.y);
                    float2 f2 = unpackh2(v.z), f3 = unpackh2(v.w);
                    acc[0] += w * f0.x;  acc[1] += w * f0.y;
                    acc[2] += w * f1.x;  acc[3] += w * f1.y;
                    acc[4] += w * f2.x;  acc[5] += w * f2.y;
                    acc[6] += w * f3.x;  acc[7] += w * f3.y;
                }
            }
            for (unsigned i = 0; i < en; ++i) {          // usually 0 entries
                if (ee[3 * i] == (unsigned)o) {
                    float w  = __uint_as_float(ee[3 * i + 2]);
                    int   ps = (int)ee[3 * i + 1];
                    #pragma unroll
                    for (int c = 0; c < CCHB; ++c)
                        acc[c] += w * inb[ps + (size_t)c * HW];
                }
            }
            size_t ob = ((size_t)n * C + cb * CCHB) * HW + opix[k];
            #pragma unroll
            for (int c = 0; c < CCHB; ++c)
                out[ob + (size_t)c * HW] = acc[c] * inv[k];
        }
    }
}

extern "C" void kernel_launch(void* const* d_in, const int* in_sizes, int n_in,
                              void* d_out, int out_size, void* d_ws, size_t ws_size,
                              hipStream_t stream)
{
    const float* tenIn     = (const float*)d_in[0];
    const float* tenFlow   = (const float*)d_in[1];
    const float* tenMetric = (const float*)d_in[2];
    float* out = (float*)d_out;

    unsigned* ws  = (unsigned*)d_ws;
    float*    den = (float*)(ws + WS_DEN);
    unsigned* meta = ws + WS_META;
    unsigned* cntg = ws + WS_CNT;
    unsigned* ovfc = ws + WS_OVFC;
    unsigned* ovfe = ws + WS_OVFE;
    unsigned* escc = ws + WS_ESCC;
    unsigned* esce = ws + WS_ESCE;

    hipMemsetAsync(ovfc, 0, TILES * sizeof(unsigned), stream);
    hipMemsetAsync(escc, 0, TILES * sizeof(unsigned), stream);

    claim_kernel<<<TILES, NTC, 0, stream>>>(tenFlow, tenMetric,
                                            meta, cntg, ovfc, ovfe, den);
    escape_kernel<<<(NPIX + 255) / 256, 256, 0, stream>>>(tenFlow, tenMetric,
                                                          den, escc, esce);
    gather_kernel<<<GGRID, NTG, 0, stream>>>(tenIn, meta, cntg, ovfc,
                                             ovfe, escc, esce, den, out);
}

// Round 10
// 391.149 us; speedup vs baseline: 1.4572x; 1.4572x over previous
//
#include <hip/hip_runtime.h>
#include <hip/hip_fp16.h>
#include <math.h>

// Problem constants: tenIn [8,64,288,512] fp32, flow [8,2,H,W], metric [8,1,H,W].
constexpr int N  = 8;
constexpr int C  = 64;
constexpr int H  = 288;
constexpr int W  = 512;               // power of 2
constexpr int HW = H * W;             // 147456
constexpr int NPIX = N * HW;          // 1,179,648

// Output tiling. R covers max corner displacement for this data; escape path
// handles anything larger exactly, so R is perf-only.
constexpr int TW = 64, TH = 32, R = 8;
constexpr int PW = TW + 2 * R;        // 80
constexpr int PH = TH + 2 * R;        // 48
constexpr int PS = PW * PH;           // 3840 (fits u16)
constexpr int TGX = W / TW;           // 8
constexpr int TGY = H / TH;           // 9
constexpr int TILES = N * TGX * TGY;  // 576
constexpr int NOUT = TH * TW;         // 2048 outputs per tile
constexpr int K = 12;                 // slots per output (zero-filled if unused)
constexpr int CCHB = 8;               // channels per gather chunk (8 x f16 = 16B)
constexpr int NCHUNK = C / CCHB;      // 8
constexpr int NSPLIT = 2;             // channel-halves across blocks
constexpr int CPB = NCHUNK / NSPLIT;  // 4 chunks per gather block
constexpr int OVFCAP = 256;           // per-tile overflow entries (slot > K)
constexpr int ESCCAP = 512;           // per-tile escape entries (|disp| > R)
constexpr int NTC = 512;              // claim threads
constexpr int NTG = 1024;             // gather threads (16 waves/block)
constexpr int GGRID = TILES * NSPLIT; // 1152 = 8 XCDs * 144

// Workspace layout (4-byte words). Total ~70.8 MB.
constexpr size_t WS_DEN  = 0;                                  // N*HW f32
constexpr size_t WS_META = WS_DEN  + (size_t)N * HW;           // TILES*K*NOUT u32 (slot-major)
constexpr size_t WS_CNT  = WS_META + (size_t)TILES * NOUT * K; // (unused, kept for layout)
constexpr size_t WS_OVFC = WS_CNT  + (size_t)TILES * NOUT;     // TILES u32
constexpr size_t WS_OVFE = WS_OVFC + TILES;                    // TILES*OVFCAP*2
constexpr size_t WS_ESCC = WS_OVFE + (size_t)TILES * OVFCAP * 2; // TILES u32
constexpr size_t WS_ESCE = WS_ESCC + TILES;                    // TILES*ESCCAP*3

__device__ __forceinline__ int swz(int si) { return si ^ ((si >> 3) & 7); }

__device__ __forceinline__ unsigned packh2(float a, float b) {
    __half2 h = __floats2half2_rn(a, b);
    return *reinterpret_cast<unsigned*>(&h);
}
__device__ __forceinline__ float2 unpackh2(unsigned u) {
    __half2 h = *reinterpret_cast<__half2*>(&u);
    return __half22float2(h);
}

// ---------------------------------------------------------------------------
// Kernel 1: per-tile claim. Each (src,corner) landing in-tile claims a slot
// via LDS atomic; meta is slot-major [t][s][o] (coalesced gather reads).
// Unused slots are ZERO-FILLED (w=0,si=0) so gather needs no counts.
// Also computes den per output (slot + overflow weight sum), plain store.
// ---------------------------------------------------------------------------
__global__ __launch_bounds__(NTC) void claim_kernel(
    const float* __restrict__ flow, const float* __restrict__ metric,
    unsigned* __restrict__ meta,
    unsigned* __restrict__ ovfc, unsigned* __restrict__ ovfe,
    float* __restrict__ den)
{
    __shared__ unsigned cnt[NOUT];     // 8 KB
    for (int i = threadIdx.x; i < NOUT; i += NTC) cnt[i] = 0;
    __syncthreads();

    const int t  = blockIdx.x;
    const int n  = t / (TGX * TGY);
    const int r  = t % (TGX * TGY);
    const int Y0 = (r / TGX) * TH;
    const int X0 = (r % TGX) * TW;

    const float* fxp = flow + ((size_t)n * 2) * HW;
    const float* fyp = fxp + HW;
    const float* mp  = metric + (size_t)n * HW;
    unsigned* mt = meta + (size_t)t * K * NOUT;

    for (int si = threadIdx.x; si < PS; si += NTC) {
        int ys = Y0 - R + si / PW;
        int xs = X0 - R + si % PW;
        if ((unsigned)ys >= (unsigned)H || (unsigned)xs >= (unsigned)W) continue;
        int p = ys * W + xs;
        float fx = fxp[p] + (float)xs;
        float fy = fyp[p] + (float)ys;
        if (!(isfinite(fx) && isfinite(fy))) continue;
        float x0f = floorf(fx), y0f = floorf(fy);
        int tx = (int)x0f - X0;
        int ty = (int)y0f - Y0;
        float wx1 = fx - x0f, wx0 = x0f + 1.0f - fx;
        float wy1 = fy - y0f, wy0 = y0f + 1.0f - fy;
        float wm  = __expf(mp[p]);

        #define CLAIM(TYv, TXv, Wv)                                           \
            if ((unsigned)(TYv) < (unsigned)TH &&                             \
                (unsigned)(TXv) < (unsigned)TW) {                             \
                float w_ = (Wv) * wm;                                         \
                int   o_ = (TYv) * TW + (TXv);                                \
                unsigned slot = atomicAdd(&cnt[o_], 1u);                      \
                if (slot < (unsigned)K) {                                     \
                    mt[(size_t)slot * NOUT + o_] =                            \
                        ((unsigned)__half_as_ushort(__float2half(w_)) << 16)  \
                        | (unsigned)si;                                       \
                } else {                                                      \
                    unsigned p2 = atomicAdd(&ovfc[t], 1u);                    \
                    if (p2 < (unsigned)OVFCAP) {                              \
                        unsigned* e = ovfe + ((size_t)t * OVFCAP + p2) * 2;   \
                        e[0] = ((unsigned)o_ << 16) | (unsigned)si;           \
                        e[1] = __float_as_uint(w_);                           \
                    }                                                         \
                }                                                             \
            }
        CLAIM(ty,     tx,     wx0 * wy0)
        CLAIM(ty,     tx + 1, wx1 * wy0)
        CLAIM(ty + 1, tx,     wx0 * wy1)
        CLAIM(ty + 1, tx + 1, wx1 * wy1)
        #undef CLAIM
    }
    __syncthreads();

    const unsigned on = min(ovfc[t], (unsigned)OVFCAP);
    const unsigned* oe = ovfe + (size_t)t * OVFCAP * 2;
    for (int o = threadIdx.x; o < NOUT; o += NTC) {
        unsigned cn = min(cnt[o], (unsigned)K);
        float d = 0.0f;
        for (unsigned s = 0; s < cn; ++s)
            d += __half2float(__ushort_as_half(
                     (unsigned short)(mt[(size_t)s * NOUT + o] >> 16)));
        for (unsigned s = cn; s < (unsigned)K; ++s)   // zero-fill unused slots
            mt[(size_t)s * NOUT + o] = 0u;
        for (unsigned i = 0; i < on; ++i)
            if ((oe[2 * i] >> 16) == (unsigned)o)
                d += __uint_as_float(oe[2 * i + 1]);
        den[(size_t)n * HW + (Y0 + o / TW) * W + X0 + o % TW] = d;
    }
}

// ---------------------------------------------------------------------------
// Kernel 2: escape (exact complement). Empty for this data.
// ---------------------------------------------------------------------------
__global__ __launch_bounds__(256) void escape_kernel(
    const float* __restrict__ flow, const float* __restrict__ metric,
    float* __restrict__ den, unsigned* __restrict__ escc,
    unsigned* __restrict__ esce)
{
    int pix = blockIdx.x * 256 + threadIdx.x;
    if (pix >= NPIX) return;
    int n  = pix / HW;
    int p  = pix - n * HW;
    int xs = p & (W - 1);
    int ys = p >> 9;

    float fx = flow[((size_t)n * 2    ) * HW + p] + (float)xs;
    float fy = flow[((size_t)n * 2 + 1) * HW + p] + (float)ys;
    if (!(isfinite(fx) && isfinite(fy))) return;
    float x0f = floorf(fx), y0f = floorf(fy);
    int ix0 = (int)x0f, iy0 = (int)y0f;
    float wx1 = fx - x0f, wx0 = x0f + 1.0f - fx;
    float wy1 = fy - y0f, wy0 = y0f + 1.0f - fy;

    int   cx[4] = { ix0, ix0 + 1, ix0,     ix0 + 1 };
    int   cy[4] = { iy0, iy0,     iy0 + 1, iy0 + 1 };
    float cw[4] = { wx0 * wy0, wx1 * wy0, wx0 * wy1, wx1 * wy1 };

    bool esc[4]; bool any = false;
    #pragma unroll
    for (int k = 0; k < 4; ++k) {
        esc[k] = false;
        if ((unsigned)cx[k] < (unsigned)W && (unsigned)cy[k] < (unsigned)H) {
            int tX0 = cx[k] & ~(TW - 1);
            int tY0 = cy[k] & ~(TH - 1);
            bool inpad = (xs >= tX0 - R) && (xs < tX0 + TW + R) &&
                         (ys >= tY0 - R) && (ys < tY0 + TH + R);
            if (!inpad) { esc[k] = true; any = true; }
        }
    }
    if (!any) return;

    float wm = __expf(metric[(size_t)n * HW + p]);
    #pragma unroll
    for (int k = 0; k < 4; ++k) {
        if (!esc[k]) continue;
        int tX0 = cx[k] & ~(TW - 1);
        int tY0 = cy[k] & ~(TH - 1);
        int tt  = n * (TGX * TGY) + (tY0 >> 5) * TGX + (tX0 >> 6);
        float w_ = cw[k] * wm;
        atomicAdd(den + (size_t)n * HW + cy[k] * W + cx[k], w_);
        unsigned pos = atomicAdd(&escc[tt], 1u);
        if (pos < (unsigned)ESCCAP) {
            unsigned* e = esce + ((size_t)tt * ESCCAP + pos) * 3;
            e[0] = (unsigned)((cy[k] - tY0) * TW + (cx[k] - tX0));
            e[1] = (unsigned)p;
            e[2] = __float_as_uint(w_);
        }
    }
}

// ---------------------------------------------------------------------------
// Kernel 3: gather + fused normalize. Block (tile t, channel-half split),
// XCD-swizzled (each XCD owns one image). LDS entry val[si] = 16B of EIGHT
// f16 channel values: one random ds_read_b128 per slot serves 8 channels.
// Meta is NOT cached across chunks (that cache was the spill driver in R9):
// per (output, chunk) the 12 slot words are reloaded coalesced from L2-hot
// slot-major meta into a short-lived local array. Staging holds at most
// 2 source planes + 4 packed words live. Live set ~50 VGPR -> fits the
// 64-reg / 2-block-per-CU allocation without scratch.
// ---------------------------------------------------------------------------
__global__ __launch_bounds__(NTG, 4) void gather_kernel(
    const float* __restrict__ in, const unsigned* __restrict__ meta,
    const unsigned* __restrict__ ovfc,
    const unsigned* __restrict__ ovfe, const unsigned* __restrict__ escc,
    const unsigned* __restrict__ esce, const float* __restrict__ den,
    float* __restrict__ out)
{
    __shared__ uint4 val[PS];   // 61440 B: 8 x f16 channels per entry

    const int b0 = blockIdx.x;
    const int b  = (b0 & 7) * (GGRID / 8) + (b0 >> 3);
    const int t     = b >> 1;
    const int split = b & 1;
    const int n  = t / (TGX * TGY);
    const int r  = t % (TGX * TGY);
    const int Y0 = (r / TGX) * TH;
    const int X0 = (r % TGX) * TW;

    const unsigned on = min(ovfc[t], (unsigned)OVFCAP);
    const unsigned en = min(escc[t], (unsigned)ESCCAP);
    const unsigned* oe = ovfe + (size_t)t * OVFCAP * 2;
    const unsigned* ee = esce + (size_t)t * ESCCAP * 3;
    const unsigned* mt = meta + (size_t)t * K * NOUT;

    float inv[2];
    int   opix[2];
    #pragma unroll
    for (int k = 0; k < 2; ++k) {
        int o = threadIdx.x + k * NTG;
        opix[k] = (Y0 + o / TW) * W + X0 + o % TW;
        float d = den[(size_t)n * HW + opix[k]];
        inv[k] = (d == 0.0f) ? 1.0f : 1.0f / d;
    }

    for (int cc = 0; cc < CPB; ++cc) {
        const int cb = split * CPB + cc;             // 8-channel group index
        const float* inb = in + ((size_t)n * C + cb * CCHB) * HW;
        __syncthreads();   // protect val from previous chunk's readers
        if (threadIdx.x < PS / 4) {        // 960 staging threads
            int si0 = threadIdx.x * 4;
            int row = si0 / PW;            // quads never straddle rows (80%4==0)
            int ys  = Y0 - R + row;
            int xs0 = X0 - R + (si0 - row * PW);
            bool ok = (unsigned)ys < (unsigned)H && (unsigned)xs0 < (unsigned)W;
            const float* pp = inb + ys * W + xs0;
            uint2* v2 = reinterpret_cast<uint2*>(val);
            int sw = (si0 >> 3) & 7;       // si0..si0+3 share swizzle bits
            {   // planes 0..3 -> low 8 bytes (channels c0..c3 as f16)
                float4 g0 = {0,0,0,0}, g1 = g0;
                if (ok) {
                    g0 = *reinterpret_cast<const float4*>(pp);
                    g1 = *reinterpret_cast<const float4*>(pp + HW);
                }
                unsigned p0 = packh2(g0.x, g1.x), p1 = packh2(g0.y, g1.y);
                unsigned p2 = packh2(g0.z, g1.z), p3 = packh2(g0.w, g1.w);
                float4 g2 = {0,0,0,0}, g3 = {0,0,0,0};
                if (ok) {
                    g2 = *reinterpret_cast<const float4*>(pp + 2 * HW);
                    g3 = *reinterpret_cast<const float4*>(pp + 3 * HW);
                }
                v2[(((si0    ) ^ sw) << 1)] = make_uint2(p0, packh2(g2.x, g3.x));
                v2[(((si0 + 1) ^ sw) << 1)] = make_uint2(p1, packh2(g2.y, g3.y));
                v2[(((si0 + 2) ^ sw) << 1)] = make_uint2(p2, packh2(g2.z, g3.z));
                v2[(((si0 + 3) ^ sw) << 1)] = make_uint2(p3, packh2(g2.w, g3.w));
            }
            {   // planes 4..7 -> high 8 bytes (channels c4..c7 as f16)
                float4 g4 = {0,0,0,0}, g5 = g4;
                if (ok) {
                    g4 = *reinterpret_cast<const float4*>(pp + 4 * HW);
                    g5 = *reinterpret_cast<const float4*>(pp + 5 * HW);
                }
                unsigned p4 = packh2(g4.x, g5.x), p5 = packh2(g4.y, g5.y);
                unsigned p6 = packh2(g4.z, g5.z), p7 = packh2(g4.w, g5.w);
                float4 g6 = {0,0,0,0}, g7 = {0,0,0,0};
                if (ok) {
                    g6 = *reinterpret_cast<const float4*>(pp + 6 * HW);
                    g7 = *reinterpret_cast<const float4*>(pp + 7 * HW);
                }
                v2[(((si0    ) ^ sw) << 1) | 1] = make_uint2(p4, packh2(g6.x, g7.x));
                v2[(((si0 + 1) ^ sw) << 1) | 1] = make_uint2(p5, packh2(g6.y, g7.y));
                v2[(((si0 + 2) ^ sw) << 1) | 1] = make_uint2(p6, packh2(g6.z, g7.z));
                v2[(((si0 + 3) ^ sw) << 1) | 1] = make_uint2(p7, packh2(g6.w, g7.w));
            }
        }
        __syncthreads();

        #pragma unroll
        for (int k = 0; k < 2; ++k) {
            const int o = threadIdx.x + k * NTG;
            const unsigned* mo = mt + o;
            unsigned mloc[K];                     // short-lived, coalesced L2 loads
            #pragma unroll
            for (int s = 0; s < K; ++s) mloc[s] = mo[(size_t)s * NOUT];

            float acc[CCHB];
            #pragma unroll
            for (int c = 0; c < CCHB; ++c) acc[c] = 0.0f;
            #pragma unroll
            for (int s = 0; s < K; ++s) {
                unsigned m_ = mloc[s];
                float w  = __half2float(__ushort_as_half((unsigned short)(m_ >> 16)));
                int   si = (int)(m_ & 0xffffu);
                uint4 v = val[swz(si)];
                float2 f0 = unpackh2(v.x), f1 = unpackh2(v.y);
                float2 f2 = unpackh2(v.z), f3 = unpackh2(v.w);
                acc[0] += w * f0.x;  acc[1] += w * f0.y;
                acc[2] += w * f1.x;  acc[3] += w * f1.y;
                acc[4] += w * f2.x;  acc[5] += w * f2.y;
                acc[6] += w * f3.x;  acc[7] += w * f3.y;
            }
            for (unsigned i = 0; i < on; ++i) {          // usually 0-3 entries
                unsigned e0 = oe[2 * i];
                if ((e0 >> 16) == (unsigned)o) {
                    float w  = __uint_as_float(oe[2 * i + 1]);
                    uint4 v = val[swz((int)(e0 & 0xffffu))];
                    float2 f0 = unpackh2(v.x), f1 = unpackh2(v.y);
                    float2 f2 = unpackh2(v.z), f3 = unpackh2(v.w);
                    acc[0] += w * f0.x;  acc[1] += w * f0.y;
                    acc[2] += w * f1.x;  acc[3] += w * f1.y;
                    acc[4] += w * f2.x;  acc[5] += w * f2.y;
                    acc[6] += w * f3.x;  acc[7] += w * f3.y;
                }
            }
            for (unsigned i = 0; i < en; ++i) {          // usually 0 entries
                if (ee[3 * i] == (unsigned)o) {
                    float w  = __uint_as_float(ee[3 * i + 2]);
                    int   ps = (int)ee[3 * i + 1];
                    #pragma unroll
                    for (int c = 0; c < CCHB; ++c)
                        acc[c] += w * inb[ps + (size_t)c * HW];
                }
            }
            size_t ob = ((size_t)n * C + cb * CCHB) * HW + opix[k];
            #pragma unroll
            for (int c = 0; c < CCHB; ++c)
                out[ob + (size_t)c * HW] = acc[c] * inv[k];
        }
    }
}

extern "C" void kernel_launch(void* const* d_in, const int* in_sizes, int n_in,
                              void* d_out, int out_size, void* d_ws, size_t ws_size,
                              hipStream_t stream)
{
    const float* tenIn     = (const float*)d_in[0];
    const float* tenFlow   = (const float*)d_in[1];
    const float* tenMetric = (const float*)d_in[2];
    float* out = (float*)d_out;

    unsigned* ws  = (unsigned*)d_ws;
    float*    den = (float*)(ws + WS_DEN);
    unsigned* meta = ws + WS_META;
    unsigned* ovfc = ws + WS_OVFC;
    unsigned* ovfe = ws + WS_OVFE;
    unsigned* escc = ws + WS_ESCC;
    unsigned* esce = ws + WS_ESCE;

    hipMemsetAsync(ovfc, 0, TILES * sizeof(unsigned), stream);
    hipMemsetAsync(escc, 0, TILES * sizeof(unsigned), stream);

    claim_kernel<<<TILES, NTC, 0, stream>>>(tenFlow, tenMetric,
                                            meta, ovfc, ovfe, den);
    escape_kernel<<<(NPIX + 255) / 256, 256, 0, stream>>>(tenFlow, tenMetric,
                                                          den, escc, esce);
    gather_kernel<<<GGRID, NTG, 0, stream>>>(tenIn, meta, ovfc,
                                             ovfe, escc, esce, den, out);
}

// Round 11
// 271.877 us; speedup vs baseline: 2.0964x; 1.4387x over previous
//
#include <hip/hip_runtime.h>
#include <hip/hip_fp16.h>
#include <math.h>

// Problem constants: tenIn [8,64,288,512] fp32, flow [8,2,H,W], metric [8,1,H,W].
constexpr int N  = 8;
constexpr int C  = 64;
constexpr int H  = 288;
constexpr int W  = 512;               // power of 2
constexpr int HW = H * W;             // 147456
constexpr int NPIX = N * HW;          // 1,179,648

// Output tiling. R covers max corner displacement for this data; escape path
// handles anything larger exactly, so R is perf-only.
constexpr int TW = 64, TH = 32, R = 8;
constexpr int PW = TW + 2 * R;        // 80
constexpr int PH = TH + 2 * R;        // 48
constexpr int PS = PW * PH;           // 3840 (fits u16)
constexpr int TGX = W / TW;           // 8
constexpr int TGY = H / TH;           // 9
constexpr int TILES = N * TGX * TGY;  // 576
constexpr int NOUT = TH * TW;         // 2048 outputs per tile
constexpr int K = 12;                 // slots per output (zero-filled if unused)
constexpr int CCHB = 4;               // channels per chunk (4 x f16 = 8B entry)
constexpr int NCHUNK = C / CCHB;      // 16
constexpr int NSPLIT = 2;             // channel-halves across blocks
constexpr int CPB = NCHUNK / NSPLIT;  // 8 chunks per gather block
constexpr int OVFCAP = 256;           // per-tile overflow entries (slot > K)
constexpr int ESCCAP = 512;           // per-tile escape entries (|disp| > R)
constexpr int NTC = 512;              // claim threads
constexpr int NTG = 1024;             // gather threads (16 waves/block)
constexpr int GGRID = TILES * NSPLIT; // 1152 = 8 XCDs * 144

// Workspace layout (4-byte words). Total ~70.8 MB.
constexpr size_t WS_DEN  = 0;                                  // N*HW f32
constexpr size_t WS_META = WS_DEN  + (size_t)N * HW;           // TILES*K*NOUT u32 (slot-major)
constexpr size_t WS_CNT  = WS_META + (size_t)TILES * NOUT * K; // (unused, kept for layout)
constexpr size_t WS_OVFC = WS_CNT  + (size_t)TILES * NOUT;     // TILES u32
constexpr size_t WS_OVFE = WS_OVFC + TILES;                    // TILES*OVFCAP*2
constexpr size_t WS_ESCC = WS_OVFE + (size_t)TILES * OVFCAP * 2; // TILES u32
constexpr size_t WS_ESCE = WS_ESCC + TILES;                    // TILES*ESCCAP*3

// Entry-index swizzle for 8B entries (bank pair = e mod 16): XOR the low
// 4 bits with bits 4..7 -> bijective within any 16-aligned block, spreads
// both the staging write pattern and random gather reads across banks.
__device__ __forceinline__ int swz(int si) { return si ^ ((si >> 4) & 15); }

__device__ __forceinline__ unsigned packh2(float a, float b) {
    __half2 h = __floats2half2_rn(a, b);
    return *reinterpret_cast<unsigned*>(&h);
}
__device__ __forceinline__ float2 unpackh2(unsigned u) {
    __half2 h = *reinterpret_cast<__half2*>(&u);
    return __half22float2(h);
}

// ---------------------------------------------------------------------------
// Kernel 1: per-tile claim. Each (src,corner) landing in-tile claims a slot
// via LDS atomic; meta is slot-major [t][s][o] (coalesced gather reads).
// Unused slots are ZERO-FILLED (w=0,si=0) so gather needs no counts.
// Also computes den per output (slot + overflow weight sum), plain store.
// ---------------------------------------------------------------------------
__global__ __launch_bounds__(NTC) void claim_kernel(
    const float* __restrict__ flow, const float* __restrict__ metric,
    unsigned* __restrict__ meta,
    unsigned* __restrict__ ovfc, unsigned* __restrict__ ovfe,
    float* __restrict__ den)
{
    __shared__ unsigned cnt[NOUT];     // 8 KB
    for (int i = threadIdx.x; i < NOUT; i += NTC) cnt[i] = 0;
    __syncthreads();

    const int t  = blockIdx.x;
    const int n  = t / (TGX * TGY);
    const int r  = t % (TGX * TGY);
    const int Y0 = (r / TGX) * TH;
    const int X0 = (r % TGX) * TW;

    const float* fxp = flow + ((size_t)n * 2) * HW;
    const float* fyp = fxp + HW;
    const float* mp  = metric + (size_t)n * HW;
    unsigned* mt = meta + (size_t)t * K * NOUT;

    for (int si = threadIdx.x; si < PS; si += NTC) {
        int ys = Y0 - R + si / PW;
        int xs = X0 - R + si % PW;
        if ((unsigned)ys >= (unsigned)H || (unsigned)xs >= (unsigned)W) continue;
        int p = ys * W + xs;
        float fx = fxp[p] + (float)xs;
        float fy = fyp[p] + (float)ys;
        if (!(isfinite(fx) && isfinite(fy))) continue;
        float x0f = floorf(fx), y0f = floorf(fy);
        int tx = (int)x0f - X0;
        int ty = (int)y0f - Y0;
        float wx1 = fx - x0f, wx0 = x0f + 1.0f - fx;
        float wy1 = fy - y0f, wy0 = y0f + 1.0f - fy;
        float wm  = __expf(mp[p]);

        #define CLAIM(TYv, TXv, Wv)                                           \
            if ((unsigned)(TYv) < (unsigned)TH &&                             \
                (unsigned)(TXv) < (unsigned)TW) {                             \
                float w_ = (Wv) * wm;                                         \
                int   o_ = (TYv) * TW + (TXv);                                \
                unsigned slot = atomicAdd(&cnt[o_], 1u);                      \
                if (slot < (unsigned)K) {                                     \
                    mt[(size_t)slot * NOUT + o_] =                            \
                        ((unsigned)__half_as_ushort(__float2half(w_)) << 16)  \
                        | (unsigned)si;                                       \
                } else {                                                      \
                    unsigned p2 = atomicAdd(&ovfc[t], 1u);                    \
                    if (p2 < (unsigned)OVFCAP) {                              \
                        unsigned* e = ovfe + ((size_t)t * OVFCAP + p2) * 2;   \
                        e[0] = ((unsigned)o_ << 16) | (unsigned)si;           \
                        e[1] = __float_as_uint(w_);                           \
                    }                                                         \
                }                                                             \
            }
        CLAIM(ty,     tx,     wx0 * wy0)
        CLAIM(ty,     tx + 1, wx1 * wy0)
        CLAIM(ty + 1, tx,     wx0 * wy1)
        CLAIM(ty + 1, tx + 1, wx1 * wy1)
        #undef CLAIM
    }
    __syncthreads();

    const unsigned on = min(ovfc[t], (unsigned)OVFCAP);
    const unsigned* oe = ovfe + (size_t)t * OVFCAP * 2;
    for (int o = threadIdx.x; o < NOUT; o += NTC) {
        unsigned cn = min(cnt[o], (unsigned)K);
        float d = 0.0f;
        for (unsigned s = 0; s < cn; ++s)
            d += __half2float(__ushort_as_half(
                     (unsigned short)(mt[(size_t)s * NOUT + o] >> 16)));
        for (unsigned s = cn; s < (unsigned)K; ++s)   // zero-fill unused slots
            mt[(size_t)s * NOUT + o] = 0u;
        for (unsigned i = 0; i < on; ++i)
            if ((oe[2 * i] >> 16) == (unsigned)o)
                d += __uint_as_float(oe[2 * i + 1]);
        den[(size_t)n * HW + (Y0 + o / TW) * W + X0 + o % TW] = d;
    }
}

// ---------------------------------------------------------------------------
// Kernel 2: escape (exact complement). Empty for this data.
// ---------------------------------------------------------------------------
__global__ __launch_bounds__(256) void escape_kernel(
    const float* __restrict__ flow, const float* __restrict__ metric,
    float* __restrict__ den, unsigned* __restrict__ escc,
    unsigned* __restrict__ esce)
{
    int pix = blockIdx.x * 256 + threadIdx.x;
    if (pix >= NPIX) return;
    int n  = pix / HW;
    int p  = pix - n * HW;
    int xs = p & (W - 1);
    int ys = p >> 9;

    float fx = flow[((size_t)n * 2    ) * HW + p] + (float)xs;
    float fy = flow[((size_t)n * 2 + 1) * HW + p] + (float)ys;
    if (!(isfinite(fx) && isfinite(fy))) return;
    float x0f = floorf(fx), y0f = floorf(fy);
    int ix0 = (int)x0f, iy0 = (int)y0f;
    float wx1 = fx - x0f, wx0 = x0f + 1.0f - fx;
    float wy1 = fy - y0f, wy0 = y0f + 1.0f - fy;

    int   cx[4] = { ix0, ix0 + 1, ix0,     ix0 + 1 };
    int   cy[4] = { iy0, iy0,     iy0 + 1, iy0 + 1 };
    float cw[4] = { wx0 * wy0, wx1 * wy0, wx0 * wy1, wx1 * wy1 };

    bool esc[4]; bool any = false;
    #pragma unroll
    for (int k = 0; k < 4; ++k) {
        esc[k] = false;
        if ((unsigned)cx[k] < (unsigned)W && (unsigned)cy[k] < (unsigned)H) {
            int tX0 = cx[k] & ~(TW - 1);
            int tY0 = cy[k] & ~(TH - 1);
            bool inpad = (xs >= tX0 - R) && (xs < tX0 + TW + R) &&
                         (ys >= tY0 - R) && (ys < tY0 + TH + R);
            if (!inpad) { esc[k] = true; any = true; }
        }
    }
    if (!any) return;

    float wm = __expf(metric[(size_t)n * HW + p]);
    #pragma unroll
    for (int k = 0; k < 4; ++k) {
        if (!esc[k]) continue;
        int tX0 = cx[k] & ~(TW - 1);
        int tY0 = cy[k] & ~(TH - 1);
        int tt  = n * (TGX * TGY) + (tY0 >> 5) * TGX + (tX0 >> 6);
        float w_ = cw[k] * wm;
        atomicAdd(den + (size_t)n * HW + cy[k] * W + cx[k], w_);
        unsigned pos = atomicAdd(&escc[tt], 1u);
        if (pos < (unsigned)ESCCAP) {
            unsigned* e = esce + ((size_t)tt * ESCCAP + pos) * 3;
            e[0] = (unsigned)((cy[k] - tY0) * TW + (cx[k] - tX0));
            e[1] = (unsigned)p;
            e[2] = __float_as_uint(w_);
        }
    }
}

// ---------------------------------------------------------------------------
// Kernel 3: gather + fused normalize. Block (tile t, channel-half split),
// XCD-swizzled (each XCD owns one image). LDS entry val[si] = 8B of FOUR f16
// channel values: random gathers are ds_read_b64 (half the bank-rounds of
// b128), and the 4-plane-per-phase staging keeps the XCD-L2 working set at
// 2.4 MB (<4 MB) so halo re-reads hit L2 (the R8 behavior, FETCH ~212 MB).
// 30 KB LDS + ~45-reg live set -> 2 blocks/CU at the 32-wave/CU cap = full
// wave occupancy with NO scratch spills. Meta reloaded per chunk (L2-hot).
// Fused 1/den; out written exactly once, coalesced.
// ---------------------------------------------------------------------------
__global__ __launch_bounds__(NTG, 4) void gather_kernel(
    const float* __restrict__ in, const unsigned* __restrict__ meta,
    const unsigned* __restrict__ ovfc,
    const unsigned* __restrict__ ovfe, const unsigned* __restrict__ escc,
    const unsigned* __restrict__ esce, const float* __restrict__ den,
    float* __restrict__ out)
{
    __shared__ uint2 val[PS];   // 30720 B: 4 x f16 channels per entry

    const int b0 = blockIdx.x;
    const int b  = (b0 & 7) * (GGRID / 8) + (b0 >> 3);
    const int t     = b >> 1;
    const int split = b & 1;
    const int n  = t / (TGX * TGY);
    const int r  = t % (TGX * TGY);
    const int Y0 = (r / TGX) * TH;
    const int X0 = (r % TGX) * TW;

    const unsigned on = min(ovfc[t], (unsigned)OVFCAP);
    const unsigned en = min(escc[t], (unsigned)ESCCAP);
    const unsigned* oe = ovfe + (size_t)t * OVFCAP * 2;
    const unsigned* ee = esce + (size_t)t * ESCCAP * 3;
    const unsigned* mt = meta + (size_t)t * K * NOUT;

    float inv[2];
    int   opix[2];
    #pragma unroll
    for (int k = 0; k < 2; ++k) {
        int o = threadIdx.x + k * NTG;
        opix[k] = (Y0 + o / TW) * W + X0 + o % TW;
        float d = den[(size_t)n * HW + opix[k]];
        inv[k] = (d == 0.0f) ? 1.0f : 1.0f / d;
    }

    for (int cc = 0; cc < CPB; ++cc) {
        const int cb = split * CPB + cc;             // 4-channel group index
        const float* inb = in + ((size_t)n * C + cb * CCHB) * HW;
        __syncthreads();   // protect val from previous chunk's readers
        if (threadIdx.x < PS / 4) {        // 960 staging threads
            int si0 = threadIdx.x * 4;
            int row = si0 / PW;            // quads never straddle rows (80%4==0)
            int ys  = Y0 - R + row;
            int xs0 = X0 - R + (si0 - row * PW);
            bool ok = (unsigned)ys < (unsigned)H && (unsigned)xs0 < (unsigned)W;
            const float* pp = inb + ys * W + xs0;
            float4 g0 = {0,0,0,0}, g1 = g0, g2 = g0, g3 = g0;
            if (ok) {
                g0 = *reinterpret_cast<const float4*>(pp);
                g1 = *reinterpret_cast<const float4*>(pp + HW);
                g2 = *reinterpret_cast<const float4*>(pp + 2 * HW);
                g3 = *reinterpret_cast<const float4*>(pp + 3 * HW);
            }
            // si0..si0+3 share (si>>4) -> same swizzle bits
            int sw = (si0 >> 4) & 15;
            val[(si0    ) ^ sw] = make_uint2(packh2(g0.x, g1.x), packh2(g2.x, g3.x));
            val[(si0 + 1) ^ sw] = make_uint2(packh2(g0.y, g1.y), packh2(g2.y, g3.y));
            val[(si0 + 2) ^ sw] = make_uint2(packh2(g0.z, g1.z), packh2(g2.z, g3.z));
            val[(si0 + 3) ^ sw] = make_uint2(packh2(g0.w, g1.w), packh2(g2.w, g3.w));
        }
        __syncthreads();

        #pragma unroll
        for (int k = 0; k < 2; ++k) {
            const int o = threadIdx.x + k * NTG;
            const unsigned* mo = mt + o;
            unsigned mloc[K];                     // short-lived, coalesced L2 loads
            #pragma unroll
            for (int s = 0; s < K; ++s) mloc[s] = mo[(size_t)s * NOUT];

            float a0 = 0.0f, a1 = 0.0f, a2 = 0.0f, a3 = 0.0f;
            #pragma unroll
            for (int s = 0; s < K; ++s) {
                unsigned m_ = mloc[s];
                float w  = __half2float(__ushort_as_half((unsigned short)(m_ >> 16)));
                int   si = (int)(m_ & 0xffffu);
                uint2 v = val[swz(si)];
                float2 f0 = unpackh2(v.x), f1 = unpackh2(v.y);
                a0 += w * f0.x;  a1 += w * f0.y;
                a2 += w * f1.x;  a3 += w * f1.y;
            }
            for (unsigned i = 0; i < on; ++i) {          // usually 0-3 entries
                unsigned e0 = oe[2 * i];
                if ((e0 >> 16) == (unsigned)o) {
                    float w  = __uint_as_float(oe[2 * i + 1]);
                    uint2 v = val[swz((int)(e0 & 0xffffu))];
                    float2 f0 = unpackh2(v.x), f1 = unpackh2(v.y);
                    a0 += w * f0.x;  a1 += w * f0.y;
                    a2 += w * f1.x;  a3 += w * f1.y;
                }
            }
            for (unsigned i = 0; i < en; ++i) {          // usually 0 entries
                if (ee[3 * i] == (unsigned)o) {
                    float w  = __uint_as_float(ee[3 * i + 2]);
                    int   ps = (int)ee[3 * i + 1];
                    a0 += w * inb[ps];
                    a1 += w * inb[ps + HW];
                    a2 += w * inb[ps + 2 * HW];
                    a3 += w * inb[ps + 3 * HW];
                }
            }
            size_t ob = ((size_t)n * C + cb * CCHB) * HW + opix[k];
            out[ob]          = a0 * inv[k];
            out[ob + HW]     = a1 * inv[k];
            out[ob + 2 * HW] = a2 * inv[k];
            out[ob + 3 * HW] = a3 * inv[k];
        }
    }
}

extern "C" void kernel_launch(void* const* d_in, const int* in_sizes, int n_in,
                              void* d_out, int out_size, void* d_ws, size_t ws_size,
                              hipStream_t stream)
{
    const float* tenIn     = (const float*)d_in[0];
    const float* tenFlow   = (const float*)d_in[1];
    const float* tenMetric = (const float*)d_in[2];
    float* out = (float*)d_out;

    unsigned* ws  = (unsigned*)d_ws;
    float*    den = (float*)(ws + WS_DEN);
    unsigned* meta = ws + WS_META;
    unsigned* ovfc = ws + WS_OVFC;
    unsigned* ovfe = ws + WS_OVFE;
    unsigned* escc = ws + WS_ESCC;
    unsigned* esce = ws + WS_ESCE;

    hipMemsetAsync(ovfc, 0, TILES * sizeof(unsigned), stream);
    hipMemsetAsync(escc, 0, TILES * sizeof(unsigned), stream);

    claim_kernel<<<TILES, NTC, 0, stream>>>(tenFlow, tenMetric,
                                            meta, ovfc, ovfe, den);
    escape_kernel<<<(NPIX + 255) / 256, 256, 0, stream>>>(tenFlow, tenMetric,
                                                          den, escc, esce);
    gather_kernel<<<GGRID, NTG, 0, stream>>>(tenIn, meta, ovfc,
                                             ovfe, escc, esce, den, out);
}

// Round 12
// 269.684 us; speedup vs baseline: 2.1135x; 1.0081x over previous
//
#include <hip/hip_runtime.h>
#include <hip/hip_fp16.h>
#include <math.h>

// Problem constants: tenIn [8,64,288,512] fp32, flow [8,2,H,W], metric [8,1,H,W].
constexpr int N  = 8;
constexpr int C  = 64;
constexpr int H  = 288;
constexpr int W  = 512;               // power of 2
constexpr int HW = H * W;             // 147456
constexpr int NPIX = N * HW;          // 1,179,648

// Output tiling. R covers max corner displacement for this data; escape path
// handles anything larger exactly, so R is perf-only.
constexpr int TW = 64, TH = 32, R = 8;
constexpr int PW = TW + 2 * R;        // 80
constexpr int PH = TH + 2 * R;        // 48
constexpr int PS = PW * PH;           // 3840 (fits u16)
constexpr int TGX = W / TW;           // 8
constexpr int TGY = H / TH;           // 9
constexpr int TILES = N * TGX * TGY;  // 576
constexpr int NOUT = TH * TW;         // 2048 outputs per tile
constexpr int K = 12;                 // slots per output (zero-filled if unused)
constexpr int CCHB = 4;               // channels per chunk (4 x f16 = 8B entry)
constexpr int NCHUNK = C / CCHB;      // 16
constexpr int NSPLIT = 2;             // channel-halves across blocks
constexpr int CPB = NCHUNK / NSPLIT;  // 8 chunks per gather block
constexpr int OVFCAP = 256;           // per-tile overflow entries (slot > K)
constexpr int ESCCAP = 512;           // per-tile escape entries (|disp| > R)
constexpr int NTC = 512;              // claim threads
constexpr int NTG = 1024;             // gather threads (16 waves/block)
constexpr int GGRID = TILES * NSPLIT; // 1152 = 8 XCDs * 144

// Workspace layout (4-byte words). Total ~70.8 MB.
constexpr size_t WS_DEN  = 0;                                  // N*HW f32
constexpr size_t WS_META = WS_DEN  + (size_t)N * HW;           // TILES*NOUT*K u32 (OUTPUT-major)
constexpr size_t WS_CNT  = WS_META + (size_t)TILES * NOUT * K; // (unused, kept for layout)
constexpr size_t WS_OVFC = WS_CNT  + (size_t)TILES * NOUT;     // TILES u32
constexpr size_t WS_OVFE = WS_OVFC + TILES;                    // TILES*OVFCAP*2
constexpr size_t WS_ESCC = WS_OVFE + (size_t)TILES * OVFCAP * 2; // TILES u32
constexpr size_t WS_ESCE = WS_ESCC + TILES;                    // TILES*ESCCAP*3

// Entry-index swizzle for 8B entries (bank pair = e mod 16): XOR the low
// 4 bits with bits 4..7 -> bijective within each 16-block, spreads staging
// writes and random reads across banks. si is PRE-swizzled at claim time.
__device__ __forceinline__ int swz(int si) { return si ^ ((si >> 4) & 15); }

__device__ __forceinline__ unsigned packh2(float a, float b) {
    __half2 h = __floats2half2_rn(a, b);
    return *reinterpret_cast<unsigned*>(&h);
}
__device__ __forceinline__ float2 unpackh2(unsigned u) {
    __half2 h = *reinterpret_cast<__half2*>(&u);
    return __half22float2(h);
}

// ---------------------------------------------------------------------------
// Kernel 1: per-tile claim. Each (src,corner) landing in-tile claims a slot
// via LDS atomic; meta is OUTPUT-major [t][o][K] (48B per output, 16B-aligned
// -> gather reads 3 coalesced uint4). si stored PRE-SWIZZLED. Unused slots
// zero-filled (w=0 -> branch-free gather). Den per output, plain store.
// ---------------------------------------------------------------------------
__global__ __launch_bounds__(NTC) void claim_kernel(
    const float* __restrict__ flow, const float* __restrict__ metric,
    unsigned* __restrict__ meta,
    unsigned* __restrict__ ovfc, unsigned* __restrict__ ovfe,
    float* __restrict__ den)
{
    __shared__ unsigned cnt[NOUT];     // 8 KB
    for (int i = threadIdx.x; i < NOUT; i += NTC) cnt[i] = 0;
    __syncthreads();

    const int t  = blockIdx.x;
    const int n  = t / (TGX * TGY);
    const int r  = t % (TGX * TGY);
    const int Y0 = (r / TGX) * TH;
    const int X0 = (r % TGX) * TW;

    const float* fxp = flow + ((size_t)n * 2) * HW;
    const float* fyp = fxp + HW;
    const float* mp  = metric + (size_t)n * HW;
    unsigned* mt = meta + (size_t)t * NOUT * K;

    for (int si = threadIdx.x; si < PS; si += NTC) {
        int ys = Y0 - R + si / PW;
        int xs = X0 - R + si % PW;
        if ((unsigned)ys >= (unsigned)H || (unsigned)xs >= (unsigned)W) continue;
        int p = ys * W + xs;
        float fx = fxp[p] + (float)xs;
        float fy = fyp[p] + (float)ys;
        if (!(isfinite(fx) && isfinite(fy))) continue;
        float x0f = floorf(fx), y0f = floorf(fy);
        int tx = (int)x0f - X0;
        int ty = (int)y0f - Y0;
        float wx1 = fx - x0f, wx0 = x0f + 1.0f - fx;
        float wy1 = fy - y0f, wy0 = y0f + 1.0f - fy;
        float wm  = __expf(mp[p]);
        int sis = swz(si);                      // pre-swizzled LDS entry index

        #define CLAIM(TYv, TXv, Wv)                                           \
            if ((unsigned)(TYv) < (unsigned)TH &&                             \
                (unsigned)(TXv) < (unsigned)TW) {                             \
                float w_ = (Wv) * wm;                                         \
                int   o_ = (TYv) * TW + (TXv);                                \
                unsigned slot = atomicAdd(&cnt[o_], 1u);                      \
                if (slot < (unsigned)K) {                                     \
                    mt[(size_t)o_ * K + slot] =                               \
                        ((unsigned)__half_as_ushort(__float2half(w_)) << 16)  \
                        | (unsigned)sis;                                      \
                } else {                                                      \
                    unsigned p2 = atomicAdd(&ovfc[t], 1u);                    \
                    if (p2 < (unsigned)OVFCAP) {                              \
                        unsigned* e = ovfe + ((size_t)t * OVFCAP + p2) * 2;   \
                        e[0] = ((unsigned)o_ << 16) | (unsigned)sis;          \
                        e[1] = __float_as_uint(w_);                           \
                    }                                                         \
                }                                                             \
            }
        CLAIM(ty,     tx,     wx0 * wy0)
        CLAIM(ty,     tx + 1, wx1 * wy0)
        CLAIM(ty + 1, tx,     wx0 * wy1)
        CLAIM(ty + 1, tx + 1, wx1 * wy1)
        #undef CLAIM
    }
    __syncthreads();

    const unsigned on = min(ovfc[t], (unsigned)OVFCAP);
    const unsigned* oe = ovfe + (size_t)t * OVFCAP * 2;
    for (int o = threadIdx.x; o < NOUT; o += NTC) {
        unsigned cn = min(cnt[o], (unsigned)K);
        float d = 0.0f;
        for (unsigned s = 0; s < cn; ++s)
            d += __half2float(__ushort_as_half(
                     (unsigned short)(mt[(size_t)o * K + s] >> 16)));
        for (unsigned s = cn; s < (unsigned)K; ++s)   // zero-fill unused slots
            mt[(size_t)o * K + s] = 0u;
        for (unsigned i = 0; i < on; ++i)
            if ((oe[2 * i] >> 16) == (unsigned)o)
                d += __uint_as_float(oe[2 * i + 1]);
        den[(size_t)n * HW + (Y0 + o / TW) * W + X0 + o % TW] = d;
    }
}

// ---------------------------------------------------------------------------
// Kernel 2: escape (exact complement). Empty for this data.
// ---------------------------------------------------------------------------
__global__ __launch_bounds__(256) void escape_kernel(
    const float* __restrict__ flow, const float* __restrict__ metric,
    float* __restrict__ den, unsigned* __restrict__ escc,
    unsigned* __restrict__ esce)
{
    int pix = blockIdx.x * 256 + threadIdx.x;
    if (pix >= NPIX) return;
    int n  = pix / HW;
    int p  = pix - n * HW;
    int xs = p & (W - 1);
    int ys = p >> 9;

    float fx = flow[((size_t)n * 2    ) * HW + p] + (float)xs;
    float fy = flow[((size_t)n * 2 + 1) * HW + p] + (float)ys;
    if (!(isfinite(fx) && isfinite(fy))) return;
    float x0f = floorf(fx), y0f = floorf(fy);
    int ix0 = (int)x0f, iy0 = (int)y0f;
    float wx1 = fx - x0f, wx0 = x0f + 1.0f - fx;
    float wy1 = fy - y0f, wy0 = y0f + 1.0f - fy;

    int   cx[4] = { ix0, ix0 + 1, ix0,     ix0 + 1 };
    int   cy[4] = { iy0, iy0,     iy0 + 1, iy0 + 1 };
    float cw[4] = { wx0 * wy0, wx1 * wy0, wx0 * wy1, wx1 * wy1 };

    bool esc[4]; bool any = false;
    #pragma unroll
    for (int k = 0; k < 4; ++k) {
        esc[k] = false;
        if ((unsigned)cx[k] < (unsigned)W && (unsigned)cy[k] < (unsigned)H) {
            int tX0 = cx[k] & ~(TW - 1);
            int tY0 = cy[k] & ~(TH - 1);
            bool inpad = (xs >= tX0 - R) && (xs < tX0 + TW + R) &&
                         (ys >= tY0 - R) && (ys < tY0 + TH + R);
            if (!inpad) { esc[k] = true; any = true; }
        }
    }
    if (!any) return;

    float wm = __expf(metric[(size_t)n * HW + p]);
    #pragma unroll
    for (int k = 0; k < 4; ++k) {
        if (!esc[k]) continue;
        int tX0 = cx[k] & ~(TW - 1);
        int tY0 = cy[k] & ~(TH - 1);
        int tt  = n * (TGX * TGY) + (tY0 >> 5) * TGX + (tX0 >> 6);
        float w_ = cw[k] * wm;
        atomicAdd(den + (size_t)n * HW + cy[k] * W + cx[k], w_);
        unsigned pos = atomicAdd(&escc[tt], 1u);
        if (pos < (unsigned)ESCCAP) {
            unsigned* e = esce + ((size_t)tt * ESCCAP + pos) * 3;
            e[0] = (unsigned)((cy[k] - tY0) * TW + (cx[k] - tX0));
            e[1] = (unsigned)p;
            e[2] = __float_as_uint(w_);
        }
    }
}

// ---------------------------------------------------------------------------
// Kernel 3: gather + fused normalize, DOUBLE-BUFFERED + async-stage split.
// Per chunk (ONE barrier): prefetch next chunk's 4 source planes into regs
// (latency hides under compute), compute current buffer (3 coalesced uint4
// meta loads + 12 random ds_read_b64 + FMAs), then pack+write the other
// buffer. 61 KB LDS + ~55-reg live set -> still 2 blocks/CU, no spills.
// ---------------------------------------------------------------------------
__global__ __launch_bounds__(NTG, 4) void gather_kernel(
    const float* __restrict__ in, const unsigned* __restrict__ meta,
    const unsigned* __restrict__ ovfc,
    const unsigned* __restrict__ ovfe, const unsigned* __restrict__ escc,
    const unsigned* __restrict__ esce, const float* __restrict__ den,
    float* __restrict__ out)
{
    __shared__ uint2 val[2][PS];   // 61440 B total

    const int b0 = blockIdx.x;
    const int b  = (b0 & 7) * (GGRID / 8) + (b0 >> 3);
    const int t     = b >> 1;
    const int split = b & 1;
    const int n  = t / (TGX * TGY);
    const int r  = t % (TGX * TGY);
    const int Y0 = (r / TGX) * TH;
    const int X0 = (r % TGX) * TW;

    const unsigned on = min(ovfc[t], (unsigned)OVFCAP);
    const unsigned en = min(escc[t], (unsigned)ESCCAP);
    const unsigned* oe = ovfe + (size_t)t * OVFCAP * 2;
    const unsigned* ee = esce + (size_t)t * ESCCAP * 3;
    const unsigned* mt = meta + (size_t)t * NOUT * K;

    float inv[2];
    int   opix[2];
    #pragma unroll
    for (int k = 0; k < 2; ++k) {
        int o = threadIdx.x + k * NTG;
        opix[k] = (Y0 + o / TW) * W + X0 + o % TW;
        float d = den[(size_t)n * HW + opix[k]];
        inv[k] = (d == 0.0f) ? 1.0f : 1.0f / d;
    }

    // Per-thread staging geometry (fixed across chunks).
    const bool stager = threadIdx.x < PS / 4;    // 960 staging threads
    int si0 = 0, sw = 0, soff = 0;
    bool ok = false;
    if (stager) {
        si0 = threadIdx.x * 4;
        int row = si0 / PW;                      // quads never straddle rows
        int ys  = Y0 - R + row;
        int xs0 = X0 - R + (si0 - row * PW);
        ok  = (unsigned)ys < (unsigned)H && (unsigned)xs0 < (unsigned)W;
        sw  = (si0 >> 4) & 15;
        soff = ys * W + xs0;
    }
    const float* inb0 = in + ((size_t)n * C + split * CPB * CCHB) * HW;

    float4 g0 = {0,0,0,0}, g1 = g0, g2 = g0, g3 = g0;
    if (stager && ok) {
        const float* pp = inb0 + soff;
        g0 = *reinterpret_cast<const float4*>(pp);
        g1 = *reinterpret_cast<const float4*>(pp + HW);
        g2 = *reinterpret_cast<const float4*>(pp + 2 * HW);
        g3 = *reinterpret_cast<const float4*>(pp + 3 * HW);
    }
    if (stager) {
        val[0][(si0    ) ^ sw] = make_uint2(packh2(g0.x, g1.x), packh2(g2.x, g3.x));
        val[0][(si0 + 1) ^ sw] = make_uint2(packh2(g0.y, g1.y), packh2(g2.y, g3.y));
        val[0][(si0 + 2) ^ sw] = make_uint2(packh2(g0.z, g1.z), packh2(g2.z, g3.z));
        val[0][(si0 + 3) ^ sw] = make_uint2(packh2(g0.w, g1.w), packh2(g2.w, g3.w));
    }

    int cur = 0;
    for (int cc = 0; cc < CPB; ++cc) {
        __syncthreads();                          // val[cur] ready for all
        const float* inb = inb0 + (size_t)cc * CCHB * HW;

        // Prefetch next chunk's planes (latency hidden under compute below).
        if (cc + 1 < CPB && stager) {
            g0 = make_float4(0,0,0,0); g1 = g0; g2 = g0; g3 = g0;
            if (ok) {
                const float* pn = inb + (size_t)CCHB * HW + soff;
                g0 = *reinterpret_cast<const float4*>(pn);
                g1 = *reinterpret_cast<const float4*>(pn + HW);
                g2 = *reinterpret_cast<const float4*>(pn + 2 * HW);
                g3 = *reinterpret_cast<const float4*>(pn + 3 * HW);
            }
        }

        const uint2* vb = val[cur];
        #pragma unroll
        for (int k = 0; k < 2; ++k) {
            const int o = threadIdx.x + k * NTG;
            const uint4* mo4 = reinterpret_cast<const uint4*>(mt + (size_t)o * K);
            uint4 qa = mo4[0], qb = mo4[1], qc = mo4[2];   // 3 coalesced loads
            unsigned mloc[K] = { qa.x, qa.y, qa.z, qa.w,
                                 qb.x, qb.y, qb.z, qb.w,
                                 qc.x, qc.y, qc.z, qc.w };

            float a0 = 0.0f, a1 = 0.0f, a2 = 0.0f, a3 = 0.0f;
            #pragma unroll
            for (int s = 0; s < K; ++s) {
                unsigned m_ = mloc[s];
                float w  = __half2float(__ushort_as_half((unsigned short)(m_ >> 16)));
                uint2 v = vb[m_ & 0xffffu];       // si pre-swizzled at claim
                float2 f0 = unpackh2(v.x), f1 = unpackh2(v.y);
                a0 += w * f0.x;  a1 += w * f0.y;
                a2 += w * f1.x;  a3 += w * f1.y;
            }
            for (unsigned i = 0; i < on; ++i) {           // usually 0-3 entries
                unsigned e0 = oe[2 * i];
                if ((e0 >> 16) == (unsigned)o) {
                    float w  = __uint_as_float(oe[2 * i + 1]);
                    uint2 v = vb[e0 & 0xffffu];
                    float2 f0 = unpackh2(v.x), f1 = unpackh2(v.y);
                    a0 += w * f0.x;  a1 += w * f0.y;
                    a2 += w * f1.x;  a3 += w * f1.y;
                }
            }
            for (unsigned i = 0; i < en; ++i) {           // usually 0 entries
                if (ee[3 * i] == (unsigned)o) {
                    float w  = __uint_as_float(ee[3 * i + 2]);
                    int   ps = (int)ee[3 * i + 1];
                    a0 += w * inb[ps];
                    a1 += w * inb[ps + HW];
                    a2 += w * inb[ps + 2 * HW];
                    a3 += w * inb[ps + 3 * HW];
                }
            }
            size_t ob = ((size_t)n * C + (split * CPB + cc) * CCHB) * HW + opix[k];
            out[ob]          = a0 * inv[k];
            out[ob + HW]     = a1 * inv[k];
            out[ob + 2 * HW] = a2 * inv[k];
            out[ob + 3 * HW] = a3 * inv[k];
        }

        // Write the prefetched planes into the other buffer (no barrier needed:
        // val[cur^1] is untouched by this iteration's readers; next iteration's
        // barrier publishes it).
        if (cc + 1 < CPB && stager) {
            uint2* vn = val[cur ^ 1];
            vn[(si0    ) ^ sw] = make_uint2(packh2(g0.x, g1.x), packh2(g2.x, g3.x));
            vn[(si0 + 1) ^ sw] = make_uint2(packh2(g0.y, g1.y), packh2(g2.y, g3.y));
            vn[(si0 + 2) ^ sw] = make_uint2(packh2(g0.z, g1.z), packh2(g2.z, g3.z));
            vn[(si0 + 3) ^ sw] = make_uint2(packh2(g0.w, g1.w), packh2(g2.w, g3.w));
        }
        cur ^= 1;
    }
}

extern "C" void kernel_launch(void* const* d_in, const int* in_sizes, int n_in,
                              void* d_out, int out_size, void* d_ws, size_t ws_size,
                              hipStream_t stream)
{
    const float* tenIn     = (const float*)d_in[0];
    const float* tenFlow   = (const float*)d_in[1];
    const float* tenMetric = (const float*)d_in[2];
    float* out = (float*)d_out;

    unsigned* ws  = (unsigned*)d_ws;
    float*    den = (float*)(ws + WS_DEN);
    unsigned* meta = ws + WS_META;
    unsigned* ovfc = ws + WS_OVFC;
    unsigned* ovfe = ws + WS_OVFE;
    unsigned* escc = ws + WS_ESCC;
    unsigned* esce = ws + WS_ESCE;

    hipMemsetAsync(ovfc, 0, TILES * sizeof(unsigned), stream);
    hipMemsetAsync(escc, 0, TILES * sizeof(unsigned), stream);

    claim_kernel<<<TILES, NTC, 0, stream>>>(tenFlow, tenMetric,
                                            meta, ovfc, ovfe, den);
    escape_kernel<<<(NPIX + 255) / 256, 256, 0, stream>>>(tenFlow, tenMetric,
                                                          den, escc, esce);
    gather_kernel<<<GGRID, NTG, 0, stream>>>(tenIn, meta, ovfc,
                                             ovfe, escc, esce, den, out);
}

// Round 13
// 233.302 us; speedup vs baseline: 2.4431x; 1.1559x over previous
//
#include <hip/hip_runtime.h>
#include <hip/hip_fp16.h>
#include <math.h>

// Problem constants: tenIn [8,64,288,512] fp32, flow [8,2,H,W], metric [8,1,H,W].
constexpr int N  = 8;
constexpr int C  = 64;
constexpr int H  = 288;
constexpr int W  = 512;               // power of 2
constexpr int HW = H * W;             // 147456
constexpr int NPIX = N * HW;          // 1,179,648

// Output tiling. R covers max corner displacement for this data; escape path
// handles anything larger exactly, so R is perf-only.
constexpr int TW = 64, TH = 32, R = 8;
constexpr int PW = TW + 2 * R;        // 80
constexpr int PH = TH + 2 * R;        // 48
constexpr int PS = PW * PH;           // 3840 (fits u16)
constexpr int TGX = W / TW;           // 8
constexpr int TGY = H / TH;           // 9
constexpr int TILES = N * TGX * TGY;  // 576
constexpr int NOUT = TH * TW;         // 2048 outputs per tile
constexpr int K = 12;                 // slots per output (zero-filled if unused)
constexpr int CCHB = 4;               // channels per chunk (4 x f16 = 8B entry)
constexpr int NCHUNK = C / CCHB;      // 16
constexpr int NSPLIT = 2;             // channel-halves across blocks
constexpr int CPB = NCHUNK / NSPLIT;  // 8 chunks per gather block
constexpr int OVFCAP = 256;           // per-tile overflow entries (slot > K)
constexpr int ESCCAP = 512;           // per-tile escape entries (|disp| > R)
constexpr int NTC = 512;              // claim threads
constexpr int NTG = 1024;             // gather threads (16 waves/block)
constexpr int GGRID = TILES * NSPLIT; // 1152 = 8 XCDs * 144

// Claim dynamic LDS: cnt[NOUT] + meta[NOUT*K], all u32.
constexpr size_t CLAIM_LDS_WORDS = (size_t)NOUT * (K + 1);      // 26624
constexpr size_t CLAIM_LDS_BYTES = CLAIM_LDS_WORDS * 4;          // 106496

// Workspace layout (4-byte words). Total ~70.8 MB.
constexpr size_t WS_DEN  = 0;                                  // N*HW f32
constexpr size_t WS_META = WS_DEN  + (size_t)N * HW;           // TILES*NOUT*K u32 (OUTPUT-major)
constexpr size_t WS_CNT  = WS_META + (size_t)TILES * NOUT * K; // (unused, kept for layout)
constexpr size_t WS_OVFC = WS_CNT  + (size_t)TILES * NOUT;     // TILES u32
constexpr size_t WS_OVFE = WS_OVFC + TILES;                    // TILES*OVFCAP*2
constexpr size_t WS_ESCC = WS_OVFE + (size_t)TILES * OVFCAP * 2; // TILES u32
constexpr size_t WS_ESCE = WS_ESCC + TILES;                    // TILES*ESCCAP*3

// Entry-index swizzle for 8B entries (bank pair = e mod 16): XOR the low
// 4 bits with bits 4..7 -> bijective within each 16-block, spreads staging
// writes and random reads across banks. si is PRE-swizzled at claim time.
__device__ __forceinline__ int swz(int si) { return si ^ ((si >> 4) & 15); }

__device__ __forceinline__ unsigned packh2(float a, float b) {
    __half2 h = __floats2half2_rn(a, b);
    return *reinterpret_cast<unsigned*>(&h);
}
__device__ __forceinline__ float2 unpackh2(unsigned u) {
    __half2 h = *reinterpret_cast<__half2*>(&u);
    return __half22float2(h);
}

// ---------------------------------------------------------------------------
// Kernel 1: per-tile claim, LDS-buffered meta. Slot claims and meta writes go
// to LDS (random 4B LDS writes instead of scattered 48B-region global
// stores); den is computed from LDS; the whole [o][K] meta block is flushed
// to global COALESCED (uint4) at the end. si stored PRE-SWIZZLED.
// ---------------------------------------------------------------------------
__global__ __launch_bounds__(NTC) void claim_kernel(
    const float* __restrict__ flow, const float* __restrict__ metric,
    unsigned* __restrict__ meta,
    unsigned* __restrict__ ovfc, unsigned* __restrict__ ovfe,
    float* __restrict__ den)
{
    extern __shared__ unsigned smem[];
    unsigned* cnt = smem;              // NOUT
    unsigned* ml  = smem + NOUT;       // NOUT*K, output-major [o][K]

    for (int i = threadIdx.x; i < NOUT; i += NTC) cnt[i] = 0;
    for (int i = threadIdx.x; i < NOUT * K; i += NTC) ml[i] = 0u;  // zero slots
    __syncthreads();

    const int t  = blockIdx.x;
    const int n  = t / (TGX * TGY);
    const int r  = t % (TGX * TGY);
    const int Y0 = (r / TGX) * TH;
    const int X0 = (r % TGX) * TW;

    const float* fxp = flow + ((size_t)n * 2) * HW;
    const float* fyp = fxp + HW;
    const float* mp  = metric + (size_t)n * HW;
    unsigned* mt = meta + (size_t)t * NOUT * K;

    for (int si = threadIdx.x; si < PS; si += NTC) {
        int ys = Y0 - R + si / PW;
        int xs = X0 - R + si % PW;
        if ((unsigned)ys >= (unsigned)H || (unsigned)xs >= (unsigned)W) continue;
        int p = ys * W + xs;
        float fx = fxp[p] + (float)xs;
        float fy = fyp[p] + (float)ys;
        if (!(isfinite(fx) && isfinite(fy))) continue;
        float x0f = floorf(fx), y0f = floorf(fy);
        int tx = (int)x0f - X0;
        int ty = (int)y0f - Y0;
        float wx1 = fx - x0f, wx0 = x0f + 1.0f - fx;
        float wy1 = fy - y0f, wy0 = y0f + 1.0f - fy;
        float wm  = __expf(mp[p]);
        int sis = swz(si);                      // pre-swizzled LDS entry index

        #define CLAIM(TYv, TXv, Wv)                                           \
            if ((unsigned)(TYv) < (unsigned)TH &&                             \
                (unsigned)(TXv) < (unsigned)TW) {                             \
                float w_ = (Wv) * wm;                                         \
                int   o_ = (TYv) * TW + (TXv);                                \
                unsigned slot = atomicAdd(&cnt[o_], 1u);                      \
                if (slot < (unsigned)K) {                                     \
                    ml[o_ * K + (int)slot] =                                  \
                        ((unsigned)__half_as_ushort(__float2half(w_)) << 16)  \
                        | (unsigned)sis;                                      \
                } else {                                                      \
                    unsigned p2 = atomicAdd(&ovfc[t], 1u);                    \
                    if (p2 < (unsigned)OVFCAP) {                              \
                        unsigned* e = ovfe + ((size_t)t * OVFCAP + p2) * 2;   \
                        e[0] = ((unsigned)o_ << 16) | (unsigned)sis;          \
                        e[1] = __float_as_uint(w_);                           \
                    }                                                         \
                }                                                             \
            }
        CLAIM(ty,     tx,     wx0 * wy0)
        CLAIM(ty,     tx + 1, wx1 * wy0)
        CLAIM(ty + 1, tx,     wx0 * wy1)
        CLAIM(ty + 1, tx + 1, wx1 * wy1)
        #undef CLAIM
    }
    __syncthreads();

    // Denominator from LDS meta + overflow list; plain coalesced-ish store.
    const unsigned on = min(ovfc[t], (unsigned)OVFCAP);
    const unsigned* oe = ovfe + (size_t)t * OVFCAP * 2;
    for (int o = threadIdx.x; o < NOUT; o += NTC) {
        unsigned cn = min(cnt[o], (unsigned)K);
        float d = 0.0f;
        for (unsigned s = 0; s < cn; ++s)
            d += __half2float(__ushort_as_half(
                     (unsigned short)(ml[o * K + (int)s] >> 16)));
        for (unsigned i = 0; i < on; ++i)
            if ((oe[2 * i] >> 16) == (unsigned)o)
                d += __uint_as_float(oe[2 * i + 1]);
        den[(size_t)n * HW + (Y0 + o / TW) * W + X0 + o % TW] = d;
    }

    // Coalesced flush of the whole meta block (6144 uint4 = 12 per thread).
    const uint4* mlv = reinterpret_cast<const uint4*>(ml);
    uint4* mtv = reinterpret_cast<uint4*>(mt);
    for (int i = threadIdx.x; i < NOUT * K / 4; i += NTC)
        mtv[i] = mlv[i];
}

// ---------------------------------------------------------------------------
// Kernel 2: escape (exact complement). Empty for this data.
// ---------------------------------------------------------------------------
__global__ __launch_bounds__(256) void escape_kernel(
    const float* __restrict__ flow, const float* __restrict__ metric,
    float* __restrict__ den, unsigned* __restrict__ escc,
    unsigned* __restrict__ esce)
{
    int pix = blockIdx.x * 256 + threadIdx.x;
    if (pix >= NPIX) return;
    int n  = pix / HW;
    int p  = pix - n * HW;
    int xs = p & (W - 1);
    int ys = p >> 9;

    float fx = flow[((size_t)n * 2    ) * HW + p] + (float)xs;
    float fy = flow[((size_t)n * 2 + 1) * HW + p] + (float)ys;
    if (!(isfinite(fx) && isfinite(fy))) return;
    float x0f = floorf(fx), y0f = floorf(fy);
    int ix0 = (int)x0f, iy0 = (int)y0f;
    float wx1 = fx - x0f, wx0 = x0f + 1.0f - fx;
    float wy1 = fy - y0f, wy0 = y0f + 1.0f - fy;

    int   cx[4] = { ix0, ix0 + 1, ix0,     ix0 + 1 };
    int   cy[4] = { iy0, iy0,     iy0 + 1, iy0 + 1 };
    float cw[4] = { wx0 * wy0, wx1 * wy0, wx0 * wy1, wx1 * wy1 };

    bool esc[4]; bool any = false;
    #pragma unroll
    for (int k = 0; k < 4; ++k) {
        esc[k] = false;
        if ((unsigned)cx[k] < (unsigned)W && (unsigned)cy[k] < (unsigned)H) {
            int tX0 = cx[k] & ~(TW - 1);
            int tY0 = cy[k] & ~(TH - 1);
            bool inpad = (xs >= tX0 - R) && (xs < tX0 + TW + R) &&
                         (ys >= tY0 - R) && (ys < tY0 + TH + R);
            if (!inpad) { esc[k] = true; any = true; }
        }
    }
    if (!any) return;

    float wm = __expf(metric[(size_t)n * HW + p]);
    #pragma unroll
    for (int k = 0; k < 4; ++k) {
        if (!esc[k]) continue;
        int tX0 = cx[k] & ~(TW - 1);
        int tY0 = cy[k] & ~(TH - 1);
        int tt  = n * (TGX * TGY) + (tY0 >> 5) * TGX + (tX0 >> 6);
        float w_ = cw[k] * wm;
        atomicAdd(den + (size_t)n * HW + cy[k] * W + cx[k], w_);
        unsigned pos = atomicAdd(&escc[tt], 1u);
        if (pos < (unsigned)ESCCAP) {
            unsigned* e = esce + ((size_t)tt * ESCCAP + pos) * 3;
            e[0] = (unsigned)((cy[k] - tY0) * TW + (cx[k] - tX0));
            e[1] = (unsigned)p;
            e[2] = __float_as_uint(w_);
        }
    }
}

// ---------------------------------------------------------------------------
// Kernel 3: gather + fused normalize, DOUBLE-BUFFERED + async-stage split.
// Per chunk (ONE barrier): prefetch next chunk's 4 source planes into regs
// (latency hides under compute), compute current buffer (3 coalesced uint4
// meta loads + 12 random ds_read_b64 + FMAs), then pack+write the other
// buffer. 61 KB LDS + ~55-reg live set -> 2 blocks/CU, no spills.
// ---------------------------------------------------------------------------
__global__ __launch_bounds__(NTG, 4) void gather_kernel(
    const float* __restrict__ in, const unsigned* __restrict__ meta,
    const unsigned* __restrict__ ovfc,
    const unsigned* __restrict__ ovfe, const unsigned* __restrict__ escc,
    const unsigned* __restrict__ esce, const float* __restrict__ den,
    float* __restrict__ out)
{
    __shared__ uint2 val[2][PS];   // 61440 B total

    const int b0 = blockIdx.x;
    const int b  = (b0 & 7) * (GGRID / 8) + (b0 >> 3);
    const int t     = b >> 1;
    const int split = b & 1;
    const int n  = t / (TGX * TGY);
    const int r  = t % (TGX * TGY);
    const int Y0 = (r / TGX) * TH;
    const int X0 = (r % TGX) * TW;

    const unsigned on = min(ovfc[t], (unsigned)OVFCAP);
    const unsigned en = min(escc[t], (unsigned)ESCCAP);
    const unsigned* oe = ovfe + (size_t)t * OVFCAP * 2;
    const unsigned* ee = esce + (size_t)t * ESCCAP * 3;
    const unsigned* mt = meta + (size_t)t * NOUT * K;

    float inv[2];
    int   opix[2];
    #pragma unroll
    for (int k = 0; k < 2; ++k) {
        int o = threadIdx.x + k * NTG;
        opix[k] = (Y0 + o / TW) * W + X0 + o % TW;
        float d = den[(size_t)n * HW + opix[k]];
        inv[k] = (d == 0.0f) ? 1.0f : 1.0f / d;
    }

    // Per-thread staging geometry (fixed across chunks).
    const bool stager = threadIdx.x < PS / 4;    // 960 staging threads
    int si0 = 0, sw = 0, soff = 0;
    bool ok = false;
    if (stager) {
        si0 = threadIdx.x * 4;
        int row = si0 / PW;                      // quads never straddle rows
        int ys  = Y0 - R + row;
        int xs0 = X0 - R + (si0 - row * PW);
        ok  = (unsigned)ys < (unsigned)H && (unsigned)xs0 < (unsigned)W;
        sw  = (si0 >> 4) & 15;
        soff = ys * W + xs0;
    }
    const float* inb0 = in + ((size_t)n * C + split * CPB * CCHB) * HW;

    float4 g0 = {0,0,0,0}, g1 = g0, g2 = g0, g3 = g0;
    if (stager && ok) {
        const float* pp = inb0 + soff;
        g0 = *reinterpret_cast<const float4*>(pp);
        g1 = *reinterpret_cast<const float4*>(pp + HW);
        g2 = *reinterpret_cast<const float4*>(pp + 2 * HW);
        g3 = *reinterpret_cast<const float4*>(pp + 3 * HW);
    }
    if (stager) {
        val[0][(si0    ) ^ sw] = make_uint2(packh2(g0.x, g1.x), packh2(g2.x, g3.x));
        val[0][(si0 + 1) ^ sw] = make_uint2(packh2(g0.y, g1.y), packh2(g2.y, g3.y));
        val[0][(si0 + 2) ^ sw] = make_uint2(packh2(g0.z, g1.z), packh2(g2.z, g3.z));
        val[0][(si0 + 3) ^ sw] = make_uint2(packh2(g0.w, g1.w), packh2(g2.w, g3.w));
    }

    int cur = 0;
    for (int cc = 0; cc < CPB; ++cc) {
        __syncthreads();                          // val[cur] ready for all
        const float* inb = inb0 + (size_t)cc * CCHB * HW;

        // Prefetch next chunk's planes (latency hidden under compute below).
        if (cc + 1 < CPB && stager) {
            g0 = make_float4(0,0,0,0); g1 = g0; g2 = g0; g3 = g0;
            if (ok) {
                const float* pn = inb + (size_t)CCHB * HW + soff;
                g0 = *reinterpret_cast<const float4*>(pn);
                g1 = *reinterpret_cast<const float4*>(pn + HW);
                g2 = *reinterpret_cast<const float4*>(pn + 2 * HW);
                g3 = *reinterpret_cast<const float4*>(pn + 3 * HW);
            }
        }

        const uint2* vb = val[cur];
        #pragma unroll
        for (int k = 0; k < 2; ++k) {
            const int o = threadIdx.x + k * NTG;
            const uint4* mo4 = reinterpret_cast<const uint4*>(mt + (size_t)o * K);
            uint4 qa = mo4[0], qb = mo4[1], qc = mo4[2];   // 3 coalesced loads
            unsigned mloc[K] = { qa.x, qa.y, qa.z, qa.w,
                                 qb.x, qb.y, qb.z, qb.w,
                                 qc.x, qc.y, qc.z, qc.w };

            float a0 = 0.0f, a1 = 0.0f, a2 = 0.0f, a3 = 0.0f;
            #pragma unroll
            for (int s = 0; s < K; ++s) {
                unsigned m_ = mloc[s];
                float w  = __half2float(__ushort_as_half((unsigned short)(m_ >> 16)));
                uint2 v = vb[m_ & 0xffffu];       // si pre-swizzled at claim
                float2 f0 = unpackh2(v.x), f1 = unpackh2(v.y);
                a0 += w * f0.x;  a1 += w * f0.y;
                a2 += w * f1.x;  a3 += w * f1.y;
            }
            for (unsigned i = 0; i < on; ++i) {           // usually 0-3 entries
                unsigned e0 = oe[2 * i];
                if ((e0 >> 16) == (unsigned)o) {
                    float w  = __uint_as_float(oe[2 * i + 1]);
                    uint2 v = vb[e0 & 0xffffu];
                    float2 f0 = unpackh2(v.x), f1 = unpackh2(v.y);
                    a0 += w * f0.x;  a1 += w * f0.y;
                    a2 += w * f1.x;  a3 += w * f1.y;
                }
            }
            for (unsigned i = 0; i < en; ++i) {           // usually 0 entries
                if (ee[3 * i] == (unsigned)o) {
                    float w  = __uint_as_float(ee[3 * i + 2]);
                    int   ps = (int)ee[3 * i + 1];
                    a0 += w * inb[ps];
                    a1 += w * inb[ps + HW];
                    a2 += w * inb[ps + 2 * HW];
                    a3 += w * inb[ps + 3 * HW];
                }
            }
            size_t ob = ((size_t)n * C + (split * CPB + cc) * CCHB) * HW + opix[k];
            out[ob]          = a0 * inv[k];
            out[ob + HW]     = a1 * inv[k];
            out[ob + 2 * HW] = a2 * inv[k];
            out[ob + 3 * HW] = a3 * inv[k];
        }

        // Write the prefetched planes into the other buffer (no barrier needed:
        // val[cur^1] is untouched by this iteration's readers; next iteration's
        // barrier publishes it).
        if (cc + 1 < CPB && stager) {
            uint2* vn = val[cur ^ 1];
            vn[(si0    ) ^ sw] = make_uint2(packh2(g0.x, g1.x), packh2(g2.x, g3.x));
            vn[(si0 + 1) ^ sw] = make_uint2(packh2(g0.y, g1.y), packh2(g2.y, g3.y));
            vn[(si0 + 2) ^ sw] = make_uint2(packh2(g0.z, g1.z), packh2(g2.z, g3.z));
            vn[(si0 + 3) ^ sw] = make_uint2(packh2(g0.w, g1.w), packh2(g2.w, g3.w));
        }
        cur ^= 1;
    }
}

extern "C" void kernel_launch(void* const* d_in, const int* in_sizes, int n_in,
                              void* d_out, int out_size, void* d_ws, size_t ws_size,
                              hipStream_t stream)
{
    const float* tenIn     = (const float*)d_in[0];
    const float* tenFlow   = (const float*)d_in[1];
    const float* tenMetric = (const float*)d_in[2];
    float* out = (float*)d_out;

    unsigned* ws  = (unsigned*)d_ws;
    float*    den = (float*)(ws + WS_DEN);
    unsigned* meta = ws + WS_META;
    unsigned* ovfc = ws + WS_OVFC;
    unsigned* ovfe = ws + WS_OVFE;
    unsigned* escc = ws + WS_ESCC;
    unsigned* esce = ws + WS_ESCE;

    // >64 KiB dynamic LDS needs the attribute raised (idempotent, capture-safe).
    hipFuncSetAttribute(reinterpret_cast<const void*>(claim_kernel),
                        hipFuncAttributeMaxDynamicSharedMemorySize,
                        (int)CLAIM_LDS_BYTES);

    hipMemsetAsync(ovfc, 0, TILES * sizeof(unsigned), stream);
    hipMemsetAsync(escc, 0, TILES * sizeof(unsigned), stream);

    claim_kernel<<<TILES, NTC, CLAIM_LDS_BYTES, stream>>>(tenFlow, tenMetric,
                                                          meta, ovfc, ovfe, den);
    escape_kernel<<<(NPIX + 255) / 256, 256, 0, stream>>>(tenFlow, tenMetric,
                                                          den, escc, esce);
    gather_kernel<<<GGRID, NTG, 0, stream>>>(tenIn, meta, ovfc,
                                             ovfe, escc, esce, den, out);
}